// Round 6
// baseline (1226.380 us; speedup 1.0000x reference)
//
#include <hip/hip_runtime.h>
#include <hip/hip_bf16.h>
#include <math.h>

#define NUSER 8192
#define NITEM 16384
#define KD 2048
#define BB 2048

typedef __bf16 bf16;
typedef __bf16 bf16x8 __attribute__((ext_vector_type(8)));
typedef float f32x4 __attribute__((ext_vector_type(4)));

// ---------------- gates: ss[K], dg[NITEM], dbg[NITEM] ----------------
__global__ __launch_bounds__(256) void gates_kernel(
    const float* __restrict__ s, const float* __restrict__ lamd_w,
    const float* __restrict__ D_w, const float* __restrict__ Db_w,
    float* __restrict__ ss, float* __restrict__ dg, float* __restrict__ dbg) {
  int i = blockIdx.x * 256 + threadIdx.x;
  if (i < NITEM) {
    dg[i] = 1.0f / (1.0f + expf(-D_w[i]));
    dbg[i] = 1.0f / (1.0f + expf(-Db_w[i]));
    if (i < KD) {
      float sv = s[i];
      ss[i] = sv / (sv + 40000.0f + 5000.0f * tanhf(lamd_w[i]));
    }
  }
}

// ---------------- A_gated[j,i] = UI[user[j],i]*(i!=pos)*drop[j,i]*dg[i] -> bf16 ----------------
__global__ __launch_bounds__(256) void prep_a_kernel(
    const float* __restrict__ UI, const float* __restrict__ drop,
    const float* __restrict__ dg, const int* __restrict__ user,
    const int* __restrict__ pos_item, bf16* __restrict__ Ag) {
  int j = blockIdx.x;
  int t = threadIdx.x;
  int uj = user[j];
  int pj = pos_item[j];
  const float* uirow = UI + (size_t)uj * NITEM;
  const float* drow = drop + (size_t)j * NITEM;
  bf16* arow = Ag + (size_t)j * NITEM;
#pragma unroll
  for (int it = 0; it < 8; ++it) {
    int i = it * 2048 + t * 8;
    float4 a0 = *(const float4*)&uirow[i];
    float4 a1 = *(const float4*)&uirow[i + 4];
    float4 d0 = *(const float4*)&drow[i];
    float4 d1 = *(const float4*)&drow[i + 4];
    float4 g0 = *(const float4*)&dg[i];
    float4 g1 = *(const float4*)&dg[i + 4];
    float v[8] = {a0.x * d0.x * g0.x, a0.y * d0.y * g0.y, a0.z * d0.z * g0.z,
                  a0.w * d0.w * g0.w, a1.x * d1.x * g1.x, a1.y * d1.y * g1.y,
                  a1.z * d1.z * g1.z, a1.w * d1.w * g1.w};
    bf16x8 o;
#pragma unroll
    for (int w = 0; w < 8; ++w) o[w] = (bf16)((i + w == pj) ? 0.0f : v[w]);
    *(bf16x8*)&arow[i] = o;
  }
}

// ---------------- Bt[k,i] = (bf16)u[i,k]  (transpose-cast via LDS) ----------------
__global__ __launch_bounds__(256) void transpose_u_kernel(
    const float* __restrict__ u, bf16* __restrict__ Bt) {
  __shared__ bf16 ldsT[64][72];
  int i0 = blockIdx.x * 64;
  int k0 = blockIdx.y * 64;
  int t = threadIdx.x;
  int r = t >> 2, q = t & 3;
#pragma unroll
  for (int cc = 0; cc < 4; ++cc) {
    int col = q * 16 + cc * 4;
    float4 v = *(const float4*)&u[(size_t)(i0 + r) * KD + k0 + col];
    ldsT[col + 0][r] = (bf16)v.x;
    ldsT[col + 1][r] = (bf16)v.y;
    ldsT[col + 2][r] = (bf16)v.z;
    ldsT[col + 3][r] = (bf16)v.w;
  }
  __syncthreads();
#pragma unroll
  for (int g = 0; g < 2; ++g) {
    int ii = q * 16 + g * 8;
    bf16x8 v = *(const bf16x8*)&ldsT[r][ii];
    *(bf16x8*)&Bt[(size_t)(k0 + r) * NITEM + i0 + ii] = v;
  }
}

// ---------------- GEMM: Y[z][j][k] = sum_{i in slice z} Ag[j,i] * Bt[k,i] ----------------
#define BM 128
#define BN 128
#define BKK 64

__global__ __launch_bounds__(256) void gemm_kernel(
    const bf16* __restrict__ A, const bf16* __restrict__ Bt,
    float* __restrict__ Y) {
  __shared__ bf16 lA[BM][BKK + 8];
  __shared__ bf16 lB[BN][BKK + 8];
  int bm = blockIdx.x * BM;
  int bn = blockIdx.y * BN;
  int kz = blockIdx.z;
  int tid = threadIdx.x;
  int wid = tid >> 6, lane = tid & 63;
  int wr = (wid >> 1) * 64, wc = (wid & 1) * 64;
  int lrow = lane & 15;
  int lko = (lane >> 4) * 8;
  f32x4 acc[4][4] = {};
  int kbeg = kz * (NITEM / 4), kend = kbeg + NITEM / 4;
  for (int kt = kbeg; kt < kend; kt += BKK) {
#pragma unroll
    for (int it = 0; it < 4; ++it) {
      int idx = tid + it * 256;
      int rr = idx >> 3, c8 = (idx & 7) * 8;
      *(bf16x8*)&lA[rr][c8] = *(const bf16x8*)&A[(size_t)(bm + rr) * NITEM + kt + c8];
      *(bf16x8*)&lB[rr][c8] = *(const bf16x8*)&Bt[(size_t)(bn + rr) * NITEM + kt + c8];
    }
    __syncthreads();
#pragma unroll
    for (int kk = 0; kk < BKK; kk += 32) {
      bf16x8 af[4], bfv[4];
#pragma unroll
      for (int m = 0; m < 4; ++m) af[m] = *(const bf16x8*)&lA[wr + m * 16 + lrow][kk + lko];
#pragma unroll
      for (int n = 0; n < 4; ++n) bfv[n] = *(const bf16x8*)&lB[wc + n * 16 + lrow][kk + lko];
#pragma unroll
      for (int m = 0; m < 4; ++m)
#pragma unroll
        for (int n = 0; n < 4; ++n)
          acc[m][n] = __builtin_amdgcn_mfma_f32_16x16x32_bf16(af[m], bfv[n], acc[m][n], 0, 0, 0);
    }
    __syncthreads();
  }
  int ccol = lane & 15, crow = (lane >> 4) * 4;
  float* yz = Y + (size_t)kz * BB * BB;
#pragma unroll
  for (int m = 0; m < 4; ++m)
#pragma unroll
    for (int n = 0; n < 4; ++n)
#pragma unroll
      for (int rix = 0; rix < 4; ++rix)
        yz[(size_t)(bm + wr + m * 16 + crow + rix) * BB + bn + wc + n * 16 + ccol] =
            acc[m][n][rix];
}

// ---------------- final: per-j gather-dots, diag correction, log-sigmoid, mean ----------------
__global__ __launch_bounds__(256) void final_kernel(
    const float* __restrict__ Y, const float* __restrict__ ss,
    const float* __restrict__ dbg, const float* __restrict__ dg,
    const float* __restrict__ vh, const float* __restrict__ u,
    const float* __restrict__ UI, const float* __restrict__ drop,
    const int* __restrict__ user, const int* __restrict__ pos_item,
    const int* __restrict__ neg_item, float* __restrict__ out) {
  int j = blockIdx.x;
  int t = threadIdx.x;
  int pj = pos_item[j], nj = neg_item[j];
  float spos = 0.0f, sneg = 0.0f, sun = 0.0f;
#pragma unroll
  for (int it = 0; it < 8; ++it) {
    int k = it * 256 + t;
    float y = Y[(size_t)j * BB + k] + Y[(size_t)(BB + j) * BB + k] +
              Y[(size_t)(2 * BB + j) * BB + k] + Y[(size_t)(3 * BB + j) * BB + k];
    float sk = ss[k];
    float gp = sk * vh[(size_t)k * NITEM + pj];
    float gn = sk * vh[(size_t)k * NITEM + nj];
    spos += y * gp;
    sneg += y * gn;
    sun += u[(size_t)nj * KD + k] * gn;
  }
  for (int o = 32; o; o >>= 1) {
    spos += __shfl_down(spos, o, 64);
    sneg += __shfl_down(sneg, o, 64);
    sun += __shfl_down(sun, o, 64);
  }
  __shared__ float red[3][4];
  int wid = t >> 6;
  if ((t & 63) == 0) { red[0][wid] = spos; red[1][wid] = sneg; red[2][wid] = sun; }
  __syncthreads();
  if (t == 0) {
    spos = red[0][0] + red[0][1] + red[0][2] + red[0][3];
    sneg = red[1][0] + red[1][1] + red[1][2] + red[1][3];
    sun = red[2][0] + red[2][1] + red[2][2] + red[2][3];
    float adiag = (nj == pj) ? 0.0f
                             : UI[(size_t)user[j] * NITEM + nj] *
                                   drop[(size_t)j * NITEM + nj] * dg[nj];
    float pos = dbg[pj] * spos;
    float neg = dbg[nj] * (sneg - adiag * sun);
    float z = 100.0f * (pos - neg);
    float lossterm = (z >= 0.0f) ? log1pf(expf(-z)) : (-z + log1pf(expf(z)));
    atomicAdd(out, lossterm * (1.0f / (float)BB));
  }
}

extern "C" void kernel_launch(void* const* d_in, const int* in_sizes, int n_in,
                              void* d_out, int out_size, void* d_ws, size_t ws_size,
                              hipStream_t stream) {
  const float* UI = (const float*)d_in[0];
  const float* u = (const float*)d_in[1];
  const float* s = (const float*)d_in[2];
  const float* vh = (const float*)d_in[3];
  const float* lamd_w = (const float*)d_in[4];
  const float* D_w = (const float*)d_in[5];
  const float* Db_w = (const float*)d_in[6];
  const float* drop = (const float*)d_in[7];
  const int* user = (const int*)d_in[8];
  const int* pos_item = (const int*)d_in[9];
  const int* neg_item = (const int*)d_in[10];
  float* out = (float*)d_out;

  char* ws = (char*)d_ws;
  size_t off = 0;
  auto alloc = [&](size_t bytes) {
    void* p = ws + off;
    off = (off + bytes + 255) & ~(size_t)255;
    return p;
  };
  float* ss = (float*)alloc((size_t)KD * 4);
  float* dg = (float*)alloc((size_t)NITEM * 4);
  float* dbg = (float*)alloc((size_t)NITEM * 4);
  bf16* Ag = (bf16*)alloc((size_t)BB * NITEM * 2);
  bf16* Bt = (bf16*)alloc((size_t)KD * NITEM * 2);
  float* Y = (float*)alloc((size_t)4 * BB * BB * 4);

  hipMemsetAsync(d_out, 0, sizeof(float), stream);
  gates_kernel<<<NITEM / 256, 256, 0, stream>>>(s, lamd_w, D_w, Db_w, ss, dg, dbg);
  prep_a_kernel<<<BB, 256, 0, stream>>>(UI, drop, dg, user, pos_item, Ag);
  transpose_u_kernel<<<dim3(NITEM / 64, KD / 64), 256, 0, stream>>>(u, Bt);
  gemm_kernel<<<dim3(BB / BM, BB / BN, 4), 256, 0, stream>>>(Ag, Bt, Y);
  final_kernel<<<BB, 256, 0, stream>>>(Y, ss, dbg, dg, vh, u, UI, drop, user,
                                       pos_item, neg_item, out);
}

// Round 7
// 1170.406 us; speedup vs baseline: 1.0478x; 1.0478x over previous
//
#include <hip/hip_runtime.h>
#include <hip/hip_bf16.h>
#include <math.h>

#define NUSER 8192
#define NITEM 16384
#define KD 2048
#define BB 2048

typedef __bf16 bf16;
typedef __bf16 bf16x8 __attribute__((ext_vector_type(8)));
typedef float f32x4 __attribute__((ext_vector_type(4)));

// async global->LDS 16B (dest = wave-uniform base + lane*16)
__device__ __forceinline__ void async16(const bf16* g, bf16* l) {
  __builtin_amdgcn_global_load_lds(
      (const __attribute__((address_space(1))) void*)g,
      (__attribute__((address_space(3))) void*)l, 16, 0, 0);
}

// ---------------- gates: ss[K], dg[NITEM], dbg[NITEM] ----------------
__global__ __launch_bounds__(256) void gates_kernel(
    const float* __restrict__ s, const float* __restrict__ lamd_w,
    const float* __restrict__ D_w, const float* __restrict__ Db_w,
    float* __restrict__ ss, float* __restrict__ dg, float* __restrict__ dbg) {
  int i = blockIdx.x * 256 + threadIdx.x;
  if (i < NITEM) {
    dg[i] = 1.0f / (1.0f + expf(-D_w[i]));
    dbg[i] = 1.0f / (1.0f + expf(-Db_w[i]));
    if (i < KD) {
      float sv = s[i];
      ss[i] = sv / (sv + 40000.0f + 5000.0f * tanhf(lamd_w[i]));
    }
  }
}

// ---------------- A_gated[j,i] = UI[user[j],i]*(i!=pos)*drop[j,i]*dg[i] -> bf16 ----------------
__global__ __launch_bounds__(256) void prep_a_kernel(
    const float* __restrict__ UI, const float* __restrict__ drop,
    const float* __restrict__ dg, const int* __restrict__ user,
    const int* __restrict__ pos_item, bf16* __restrict__ Ag) {
  int j = blockIdx.x;
  int t = threadIdx.x;
  int uj = user[j];
  int pj = pos_item[j];
  const float* uirow = UI + (size_t)uj * NITEM;
  const float* drow = drop + (size_t)j * NITEM;
  bf16* arow = Ag + (size_t)j * NITEM;
#pragma unroll
  for (int it = 0; it < 8; ++it) {
    int i = it * 2048 + t * 8;
    float4 a0 = *(const float4*)&uirow[i];
    float4 a1 = *(const float4*)&uirow[i + 4];
    float4 d0 = *(const float4*)&drow[i];
    float4 d1 = *(const float4*)&drow[i + 4];
    float4 g0 = *(const float4*)&dg[i];
    float4 g1 = *(const float4*)&dg[i + 4];
    float v[8] = {a0.x * d0.x * g0.x, a0.y * d0.y * g0.y, a0.z * d0.z * g0.z,
                  a0.w * d0.w * g0.w, a1.x * d1.x * g1.x, a1.y * d1.y * g1.y,
                  a1.z * d1.z * g1.z, a1.w * d1.w * g1.w};
    bf16x8 o;
#pragma unroll
    for (int w = 0; w < 8; ++w) o[w] = (bf16)((i + w == pj) ? 0.0f : v[w]);
    *(bf16x8*)&arow[i] = o;
  }
}

// ---------------- Bt[k,i] = (bf16)u[i,k]  (transpose-cast via LDS) ----------------
__global__ __launch_bounds__(256) void transpose_u_kernel(
    const float* __restrict__ u, bf16* __restrict__ Bt) {
  __shared__ bf16 ldsT[64][72];
  int i0 = blockIdx.x * 64;
  int k0 = blockIdx.y * 64;
  int t = threadIdx.x;
  int r = t >> 2, q = t & 3;
#pragma unroll
  for (int cc = 0; cc < 4; ++cc) {
    int col = q * 16 + cc * 4;
    float4 v = *(const float4*)&u[(size_t)(i0 + r) * KD + k0 + col];
    ldsT[col + 0][r] = (bf16)v.x;
    ldsT[col + 1][r] = (bf16)v.y;
    ldsT[col + 2][r] = (bf16)v.z;
    ldsT[col + 3][r] = (bf16)v.w;
  }
  __syncthreads();
#pragma unroll
  for (int g = 0; g < 2; ++g) {
    int ii = q * 16 + g * 8;
    bf16x8 v = *(const bf16x8*)&ldsT[r][ii];
    *(bf16x8*)&Bt[(size_t)(k0 + r) * NITEM + i0 + ii] = v;
  }
}

// ---------------- vhT[i,k] = ss[k] * vh[k,i]  (fp32 transpose, ss folded) ----------------
__global__ __launch_bounds__(256) void transpose_vh_kernel(
    const float* __restrict__ vh, const float* __restrict__ ss,
    float* __restrict__ vhT) {
  __shared__ float tile[64][65];
  int i0 = blockIdx.x * 64;  // item cols of vh
  int k0 = blockIdx.y * 64;  // k rows of vh
  int t = threadIdx.x;
  int r = t >> 4, c4 = (t & 15) * 4;
#pragma unroll
  for (int p = 0; p < 4; ++p) {
    int row = p * 16 + r;
    float4 v = *(const float4*)&vh[(size_t)(k0 + row) * NITEM + i0 + c4];
    float sk = ss[k0 + row];
    tile[c4 + 0][row] = v.x * sk;
    tile[c4 + 1][row] = v.y * sk;
    tile[c4 + 2][row] = v.z * sk;
    tile[c4 + 3][row] = v.w * sk;
  }
  __syncthreads();
#pragma unroll
  for (int p = 0; p < 4; ++p) {
    int row = p * 16 + r;  // item row of vhT
    float4 o;
    o.x = tile[row][c4 + 0];
    o.y = tile[row][c4 + 1];
    o.z = tile[row][c4 + 2];
    o.w = tile[row][c4 + 3];
    *(float4*)&vhT[(size_t)(i0 + row) * KD + k0 + c4] = o;
  }
}

// ---------------- GEMM (m97 structure): Y[z][j][k] = sum_{i in slice z} Ag[j,i]*Bt[k,i] ----------------
#define BM 128
#define BN 128
#define BKK 64

__global__ __launch_bounds__(256) void gemm_kernel(
    const bf16* __restrict__ A, const bf16* __restrict__ Bt,
    float* __restrict__ Y) {
  __shared__ bf16 lA[BM][BKK];  // linear: global_load_lds dest must be unpadded
  __shared__ bf16 lB[BN][BKK];
  int bm = blockIdx.x * BM;
  int bn = blockIdx.y * BN;
  int kz = blockIdx.z;
  int tid = threadIdx.x;
  int wid = tid >> 6, lane = tid & 63;
  int wr = (wid >> 1) * 64, wc = (wid & 1) * 64;
  int lrow = lane & 15;
  int lko = (lane >> 4) * 8;
  f32x4 acc[4][4] = {};
  int kbeg = kz * (NITEM / 4), kend = kbeg + NITEM / 4;
  for (int kt = kbeg; kt < kend; kt += BKK) {
    // stage 16KB A + 16KB B: 4 issues x 256 threads x 16B each
#pragma unroll
    for (int it = 0; it < 4; ++it) {
      int idx = it * 256 + tid;
      int rr = idx >> 3, c8 = (idx & 7) * 8;
      int base = it * 256 + (tid & ~63);  // wave-uniform segment start (elements/8)
      async16(&A[(size_t)(bm + rr) * NITEM + kt + c8], &((bf16*)lA)[(size_t)base * 8]);
      async16(&Bt[(size_t)(bn + rr) * NITEM + kt + c8], &((bf16*)lB)[(size_t)base * 8]);
    }
    __syncthreads();  // compiler drains vmcnt(0) before s_barrier
#pragma unroll
    for (int kk = 0; kk < BKK; kk += 32) {
      bf16x8 af[4], bfv[4];
#pragma unroll
      for (int m = 0; m < 4; ++m) af[m] = *(const bf16x8*)&lA[wr + m * 16 + lrow][kk + lko];
#pragma unroll
      for (int n = 0; n < 4; ++n) bfv[n] = *(const bf16x8*)&lB[wc + n * 16 + lrow][kk + lko];
#pragma unroll
      for (int m = 0; m < 4; ++m)
#pragma unroll
        for (int n = 0; n < 4; ++n)
          acc[m][n] = __builtin_amdgcn_mfma_f32_16x16x32_bf16(af[m], bfv[n], acc[m][n], 0, 0, 0);
    }
    __syncthreads();
  }
  int ccol = lane & 15, crow = (lane >> 4) * 4;
  float* yz = Y + (size_t)kz * BB * BB;
#pragma unroll
  for (int m = 0; m < 4; ++m)
#pragma unroll
    for (int n = 0; n < 4; ++n)
#pragma unroll
      for (int rix = 0; rix < 4; ++rix)
        yz[(size_t)(bm + wr + m * 16 + crow + rix) * BB + bn + wc + n * 16 + ccol] =
            acc[m][n][rix];
}

// ---------------- final: coalesced row-dots vs vhT, diag correction, log-sigmoid, mean ----------------
__global__ __launch_bounds__(256) void final_kernel(
    const float* __restrict__ Y, const float* __restrict__ vhT,
    const float* __restrict__ dbg, const float* __restrict__ dg,
    const float* __restrict__ u, const float* __restrict__ UI,
    const float* __restrict__ drop, const int* __restrict__ user,
    const int* __restrict__ pos_item, const int* __restrict__ neg_item,
    float* __restrict__ out) {
  int j = blockIdx.x;
  int t = threadIdx.x;
  int pj = pos_item[j], nj = neg_item[j];
  const float* vp = vhT + (size_t)pj * KD;
  const float* vn = vhT + (size_t)nj * KD;
  const float* un = u + (size_t)nj * KD;
  float spos = 0.0f, sneg = 0.0f, sun = 0.0f;
#pragma unroll
  for (int it = 0; it < 8; ++it) {
    int k = it * 256 + t;
    float y = Y[(size_t)j * BB + k] + Y[(size_t)(BB + j) * BB + k] +
              Y[(size_t)(2 * BB + j) * BB + k] + Y[(size_t)(3 * BB + j) * BB + k];
    float gp = vp[k];  // ss already folded into vhT
    float gn = vn[k];
    spos += y * gp;
    sneg += y * gn;
    sun += un[k] * gn;
  }
  for (int o = 32; o; o >>= 1) {
    spos += __shfl_down(spos, o, 64);
    sneg += __shfl_down(sneg, o, 64);
    sun += __shfl_down(sun, o, 64);
  }
  __shared__ float red[3][4];
  int wid = t >> 6;
  if ((t & 63) == 0) { red[0][wid] = spos; red[1][wid] = sneg; red[2][wid] = sun; }
  __syncthreads();
  if (t == 0) {
    spos = red[0][0] + red[0][1] + red[0][2] + red[0][3];
    sneg = red[1][0] + red[1][1] + red[1][2] + red[1][3];
    sun = red[2][0] + red[2][1] + red[2][2] + red[2][3];
    float adiag = (nj == pj) ? 0.0f
                             : UI[(size_t)user[j] * NITEM + nj] *
                                   drop[(size_t)j * NITEM + nj] * dg[nj];
    float pos = dbg[pj] * spos;
    float neg = dbg[nj] * (sneg - adiag * sun);
    float z = 100.0f * (pos - neg);
    float lossterm = (z >= 0.0f) ? log1pf(expf(-z)) : (-z + log1pf(expf(z)));
    atomicAdd(out, lossterm * (1.0f / (float)BB));
  }
}

extern "C" void kernel_launch(void* const* d_in, const int* in_sizes, int n_in,
                              void* d_out, int out_size, void* d_ws, size_t ws_size,
                              hipStream_t stream) {
  const float* UI = (const float*)d_in[0];
  const float* u = (const float*)d_in[1];
  const float* s = (const float*)d_in[2];
  const float* vh = (const float*)d_in[3];
  const float* lamd_w = (const float*)d_in[4];
  const float* D_w = (const float*)d_in[5];
  const float* Db_w = (const float*)d_in[6];
  const float* drop = (const float*)d_in[7];
  const int* user = (const int*)d_in[8];
  const int* pos_item = (const int*)d_in[9];
  const int* neg_item = (const int*)d_in[10];
  float* out = (float*)d_out;

  char* ws = (char*)d_ws;
  size_t off = 0;
  auto alloc = [&](size_t bytes) {
    void* p = ws + off;
    off = (off + bytes + 255) & ~(size_t)255;
    return p;
  };
  float* ss = (float*)alloc((size_t)KD * 4);
  float* dg = (float*)alloc((size_t)NITEM * 4);
  float* dbg = (float*)alloc((size_t)NITEM * 4);
  bf16* Ag = (bf16*)alloc((size_t)BB * NITEM * 2);
  bf16* Bt = (bf16*)alloc((size_t)KD * NITEM * 2);
  float* Y = (float*)alloc((size_t)4 * BB * BB * 4);
  float* vhT = (float*)alloc((size_t)NITEM * KD * 4);

  hipMemsetAsync(d_out, 0, sizeof(float), stream);
  gates_kernel<<<NITEM / 256, 256, 0, stream>>>(s, lamd_w, D_w, Db_w, ss, dg, dbg);
  prep_a_kernel<<<BB, 256, 0, stream>>>(UI, drop, dg, user, pos_item, Ag);
  transpose_u_kernel<<<dim3(NITEM / 64, KD / 64), 256, 0, stream>>>(u, Bt);
  transpose_vh_kernel<<<dim3(NITEM / 64, KD / 64), 256, 0, stream>>>(vh, ss, vhT);
  gemm_kernel<<<dim3(BB / BM, BB / BN, 4), 256, 0, stream>>>(Ag, Bt, Y);
  final_kernel<<<BB, 256, 0, stream>>>(Y, vhT, dbg, dg, u, UI, drop, user,
                                       pos_item, neg_item, out);
}